// Round 24
// baseline (129.756 us; speedup 1.0000x reference)
//
#include <hip/hip_runtime.h>
#include <hip/hip_bf16.h>

typedef __attribute__((ext_vector_type(4))) float f32x4;
typedef __attribute__((ext_vector_type(4))) unsigned u32x4;
typedef __attribute__((ext_vector_type(8))) short bf16x8;

#define QSCALE  (0.03608439182435161f * 1.44269504088896f)  // 768^-0.5 * log2(e)

__device__ __forceinline__ unsigned short f2bf(float f) {
    union { float f; unsigned u; } v; v.f = f;
    return (unsigned short)((v.u + 0x7FFFu + ((v.u >> 16) & 1u)) >> 16);
}

__device__ __forceinline__ float fast_exp2(float x) {
#if __has_builtin(__builtin_amdgcn_exp2f)
    return __builtin_amdgcn_exp2f(x);
#else
    return exp2f(x);
#endif
}

__device__ __forceinline__ void gload_lds16(const void* g, void* l) {
    __builtin_amdgcn_global_load_lds(
        (const __attribute__((address_space(1))) unsigned int*)g,
        (__attribute__((address_space(3))) unsigned int*)l, 16, 0, 0);
}

// ---------------------------------------------------------------------------
// Fused prepass: blocks [0,3072) xcvt X; [3072,3504) wtrans Wqkv;
// [3504,3648) wtrans Wout. Block-uniform branch.
// ---------------------------------------------------------------------------
__global__ __launch_bounds__(256) void prep_kernel(
    const float* __restrict__ X, unsigned short* __restrict__ Xb,
    const float* __restrict__ Wqkv, unsigned short* __restrict__ WqkvT,
    const float* __restrict__ Wout, unsigned short* __restrict__ WoutT)
{
    __shared__ unsigned short T[64][68];
    const int bid = blockIdx.x, t = threadIdx.x;

    if (bid < 3072) {                      // ---- xcvt: X fp32 -> bf16
        const int i = bid * 256 + t;
        f32x4 a = *(const f32x4*)(X + (size_t)i * 8);
        f32x4 b = *(const f32x4*)(X + (size_t)i * 8 + 4);
        bf16x8 w;
#pragma unroll
        for (int j = 0; j < 4; ++j) { w[j] = (short)f2bf(a[j]); w[4 + j] = (short)f2bf(b[j]); }
        *(bf16x8*)(Xb + (size_t)i * 8) = w;
        return;
    }

    const float* W; unsigned short* WT; int C, bx, by;
    if (bid < 3504) { W = Wqkv; WT = WqkvT; C = 2304; const int x = bid - 3072; bx = x % 36; by = x / 36; }
    else            { W = Wout; WT = WoutT; C = 768;  const int x = bid - 3504; bx = x % 12; by = x / 12; }
    const int R = 768;
    const int r0 = by * 64, c0 = bx * 64;
    {
        const int lr = t >> 4, lc = (t & 15) * 4;
#pragma unroll
        for (int p = 0; p < 4; ++p) {
            const float* s = W + (size_t)(r0 + lr + p * 16) * C + c0 + lc;
            f32x4 v = *(const f32x4*)s;
            unsigned short* d = &T[lr + p * 16][lc];
            d[0] = f2bf(v[0]); d[1] = f2bf(v[1]); d[2] = f2bf(v[2]); d[3] = f2bf(v[3]);
        }
    }
    __syncthreads();
    {
        const int oc = t >> 3, j0 = (t & 7) * 8;
#pragma unroll
        for (int p = 0; p < 2; ++p) {
            const int c = oc + p * 32;
            bf16x8 v;
#pragma unroll
            for (int j = 0; j < 8; ++j) v[j] = (short)T[j0 + j][c];
            *(bf16x8*)(WT + (size_t)(c0 + c) * R + r0 + j0) = v;
        }
    }
}

// ---------------------------------------------------------------------------
// Kernel 1: QKV = Xb @ WqkvT^T + b  (M=8192, K=768, N=2304). r23 proven:
// 128x128 tile, QUAD-buffered LDS (64KB), depth-2 prefetch, vmcnt(8),
// ONE barrier/iter, unroll-by-4. Epilogues: Q/K LDS restage, V transpose.
// ---------------------------------------------------------------------------
__global__ __launch_bounds__(256) void qkv_gemm_kernel(
    const unsigned short* __restrict__ Xb, const unsigned short* __restrict__ WT,
    const float* __restrict__ bias,
    unsigned short* __restrict__ Qw, unsigned short* __restrict__ Kw,
    unsigned short* __restrict__ VTw)
{
    __shared__ unsigned short SMEM[4 * 8192];

    const int t = threadIdx.x;
    const int lane = t & 63, wave = t >> 6;
    const int l15 = lane & 15, l4 = lane >> 4;
    const int m0 = blockIdx.x * 128, n0 = blockIdx.y * 128;
    const int wr = wave >> 1, wc = wave & 1;

    f32x4 acc[4][4];
#pragma unroll
    for (int m = 0; m < 4; ++m)
#pragma unroll
        for (int n = 0; n < 4; ++n) acc[m][n] = (f32x4){0.f, 0.f, 0.f, 0.f};

    auto STAGE = [&](int k0, int bufi) {
        char* base = (char*)SMEM + bufi * 16384;
#pragma unroll
        for (int c = 0; c < 2; ++c) {
            const int o = wave * 1024 + lane * 16 + c * 4096;
            const int row = o >> 6, cb = o & 63;
            gload_lds16((const char*)(Xb + (size_t)(m0 + row) * 768 + k0) + cb,
                        base + wave * 1024 + c * 4096);
            gload_lds16((const char*)(WT + (size_t)(n0 + row) * 768 + k0) + cb,
                        base + 8192 + wave * 1024 + c * 4096);
        }
    };

    STAGE(0, 0);
    STAGE(32, 1);                 // depth-2 prologue: tiles 0,1 in flight
    for (int g = 0; g < 6; ++g) {
#pragma unroll
        for (int p = 0; p < 4; ++p) {
            const int k = g * 4 + p;
            if (k < 22) {
                STAGE((k + 2) * 32, (k + 2) & 3);
                asm volatile("s_waitcnt vmcnt(8)" ::: "memory");
            } else if (k == 22) {
                asm volatile("s_waitcnt vmcnt(4)" ::: "memory");
            } else {
                asm volatile("s_waitcnt vmcnt(0)" ::: "memory");
            }
            __builtin_amdgcn_s_barrier();
            __builtin_amdgcn_sched_barrier(0);

            const char* base = (const char*)SMEM + p * 16384;
            bf16x8 af[4], bfr[4];
#pragma unroll
            for (int m = 0; m < 4; ++m)
                af[m] = *(const bf16x8*)(base + (wr * 64 + m * 16 + l15) * 64 + l4 * 16);
#pragma unroll
            for (int n = 0; n < 4; ++n)
                bfr[n] = *(const bf16x8*)(base + 8192 + (wc * 64 + n * 16 + l15) * 64 + l4 * 16);
            __builtin_amdgcn_s_setprio(1);
#pragma unroll
            for (int m = 0; m < 4; ++m)
#pragma unroll
                for (int n = 0; n < 4; ++n)
                    acc[m][n] = __builtin_amdgcn_mfma_f32_16x16x32_bf16(af[m], bfr[n], acc[m][n], 0, 0, 0);
            __builtin_amdgcn_s_setprio(0);
        }
    }
    __syncthreads();

    const int b = m0 >> 10, ntok0 = m0 & 1023;
    if (n0 < 1536) {
        const int which = n0 / 768;
        const int h0 = (n0 - which * 768) >> 6;
#pragma unroll
        for (int hh = 0; hh < 2; ++hh) {
            if (wc == hh) {
#pragma unroll
                for (int n = 0; n < 4; ++n) {
                    const int dd = n * 16 + l15;
                    const float bv = bias[n0 + hh * 64 + dd];
#pragma unroll
                    for (int m = 0; m < 4; ++m)
#pragma unroll
                        for (int r = 0; r < 4; ++r) {
                            const int ntl = wr * 64 + m * 16 + l4 * 4 + r;
                            float val = acc[m][n][r] + bv;
                            if (which == 0) val *= QSCALE;
                            SMEM[ntl * 68 + dd] = f2bf(val);
                        }
                }
            }
            __syncthreads();
            {
                unsigned short* dst = (which == 0 ? Qw : Kw)
                    + ((size_t)(b * 12 + h0 + hh) * 1024 + ntok0) * 64;
                const int k8 = (t & 7) * 8;
#pragma unroll
                for (int pass = 0; pass < 4; ++pass) {
                    const int row = pass * 32 + (t >> 3);
                    *(bf16x8*)&dst[(size_t)row * 64 + k8] =
                        *(const bf16x8*)&SMEM[row * 68 + k8];
                }
            }
            __syncthreads();
        }
    } else {
        const int h0 = (n0 - 1536) >> 6;
#pragma unroll
        for (int hh = 0; hh < 2; ++hh) {
            if (wc == hh) {
#pragma unroll
                for (int n = 0; n < 4; ++n) {
                    const int cloc = n * 16 + l15;
                    const float bv = bias[n0 + hh * 64 + cloc];
#pragma unroll
                    for (int m = 0; m < 4; ++m)
#pragma unroll
                        for (int r = 0; r < 4; ++r) {
                            const int ntl = wr * 64 + m * 16 + l4 * 4 + r;
                            SMEM[cloc * 136 + ntl] = f2bf(acc[m][n][r] + bv);
                        }
                }
            }
            __syncthreads();
            {
                const int sub = t & 15;
#pragma unroll
                for (int rep = 0; rep < 4; ++rep) {
                    const int cll = rep * 16 + (t >> 4);
                    const size_t rb = ((size_t)(b * 12 + h0 + hh) * 64 + cll) * 1024
                                      + ntok0 + sub * 8;
                    *(bf16x8*)&VTw[rb] = *(const bf16x8*)&SMEM[cll * 136 + sub * 8];
                }
            }
            __syncthreads();
        }
    }
}

// ---------------------------------------------------------------------------
// Kernel 2: flash attention, QBLK=128. NEW: TRIPLE-buffered K/V LDS with
// ONE barrier/iter (restage of buf[(kt+1)%3] separated from its last read
// at compute(kt-2) by barrier(kt-1) -- same proof as qkv quad-buffer).
// 5x3 grouped unroll + epilogue iter keeps buffer indices static.
// Sigma-permuted K rows -> P in registers; exp2 softmax; defer-max;
// counted vmcnt(4); XCD-bijective swizzle (8x96); setprio on MFMA.
// ---------------------------------------------------------------------------
__global__ __launch_bounds__(256) void attn_kernel(
    const unsigned short* __restrict__ Qw, const unsigned short* __restrict__ Kw,
    const unsigned short* __restrict__ VTw, unsigned short* __restrict__ A2)
{
    __shared__ unsigned short Klds[3 * 64 * 64];    // 24KB
    __shared__ unsigned short Vlds[3 * 64 * 64];    // 24KB
    __shared__ float Flds[4 * 2 * 16];

    const int t = threadIdx.x, lane = t & 63, wave = t >> 6;
    const int l15 = lane & 15, l4 = lane >> 4;
    const int wg = (blockIdx.x & 7) * 96 + (blockIdx.x >> 3);   // 768 = 8 XCD x 96
    const int qt = wg & 7, bh = wg >> 3;
    const int q0 = qt * 128;

    const size_t kvbase = (size_t)bh * 1024 * 64;
    const size_t vtbase = (size_t)bh * 64 * 1024;

    bf16x8 qf[2][2];
#pragma unroll
    for (int qs = 0; qs < 2; ++qs) {
        const unsigned short* qptr = Qw + kvbase + (size_t)(q0 + qs * 64 + wave * 16 + l15) * 64;
        qf[qs][0] = *(const bf16x8*)((const char*)qptr + l4 * 16);
        qf[qs][1] = *(const bf16x8*)((const char*)qptr + 64 + l4 * 16);
    }

    f32x4 oacc[2][4];
#pragma unroll
    for (int qs = 0; qs < 2; ++qs)
#pragma unroll
        for (int d = 0; d < 4; ++d) oacc[qs][d] = (f32x4){0.f, 0.f, 0.f, 0.f};
    float m_run[2] = {-1e30f, -1e30f}, l_run[2] = {0.f, 0.f};

    auto STAGE = [&](int kt, int bufi) {
        const int kv0 = kt * 64;
        char* kb = (char*)Klds + bufi * 8192;
        char* vb = (char*)Vlds + bufi * 8192;
#pragma unroll
        for (int c = 0; c < 2; ++c) {
            const int oo = wave * 1024 + lane * 16 + c * 4096;
            const int R = oo >> 7, w = oo & 127;
            const int sw = w ^ ((R & 7) << 4);
            const int kvs = (R & 0x23) | ((R & 0x0C) << 1) | ((R & 0x10) >> 2);
            gload_lds16((const char*)(Kw + kvbase + (size_t)(kv0 + kvs) * 64) + sw,
                        kb + wave * 1024 + c * 4096);
            gload_lds16((const char*)(VTw + vtbase + (size_t)R * 1024 + kv0) + sw,
                        vb + wave * 1024 + c * 4096);
        }
    };

    // one-iteration body: stage next (unless last), counted wait, ONE barrier,
    // then QK+softmax+PV on buffer `cur` (compile-time constant).
    auto BODY = [&](int kt, int cur, bool last) {
        if (!last) {
            STAGE(kt + 1, (cur + 1) % 3);
            asm volatile("s_waitcnt vmcnt(4)" ::: "memory");  // tile kt landed
        } else {
            asm volatile("s_waitcnt vmcnt(0)" ::: "memory");
        }
        __builtin_amdgcn_s_barrier();
        __builtin_amdgcn_sched_barrier(0);
        const char* kb = (const char*)Klds + cur * 8192;
        const char* vb = (const char*)Vlds + cur * 8192;

#pragma unroll
        for (int qs = 0; qs < 2; ++qs) {
            f32x4 sacc[4];
#pragma unroll
            for (int i = 0; i < 4; ++i) sacc[i] = (f32x4){0.f, 0.f, 0.f, 0.f};
            __builtin_amdgcn_s_setprio(1);
#pragma unroll
            for (int ks = 0; ks < 2; ++ks) {
                const bf16x8 qq = qf[qs][ks];
#pragma unroll
                for (int kvf = 0; kvf < 4; ++kvf) {
                    const int row = kvf * 16 + l15;
                    int addr = row * 128 + ks * 64 + l4 * 16;
                    addr ^= (row & 7) << 4;
                    const bf16x8 kf = *(const bf16x8*)(kb + addr);
                    sacc[kvf] = __builtin_amdgcn_mfma_f32_16x16x32_bf16(kf, qq, sacc[kvf], 0, 0, 0);
                }
            }
            __builtin_amdgcn_s_setprio(0);

            float p[16];
            float tmax = -1e30f;
#pragma unroll
            for (int i = 0; i < 4; ++i)
#pragma unroll
                for (int r = 0; r < 4; ++r) {
                    p[i * 4 + r] = sacc[i][r];
                    tmax = fmaxf(tmax, sacc[i][r]);
                }
            tmax = fmaxf(tmax, __shfl_xor(tmax, 16));
            tmax = fmaxf(tmax, __shfl_xor(tmax, 32));

            if (!__all(tmax - m_run[qs] <= 8.f)) {
                const float mnew = fmaxf(m_run[qs], tmax);
                const float alpha = fast_exp2(m_run[qs] - mnew);
                m_run[qs] = mnew;
                if (lane < 16) Flds[wave * 32 + qs * 16 + lane] = alpha;
                const f32x4 av = *(const f32x4*)(&Flds[wave * 32 + qs * 16 + l4 * 4]);
#pragma unroll
                for (int d = 0; d < 4; ++d)
#pragma unroll
                    for (int r = 0; r < 4; ++r) oacc[qs][d][r] *= av[r];
                l_run[qs] *= alpha;
            }

            float tsum = 0.f;
#pragma unroll
            for (int i = 0; i < 16; ++i) { p[i] = fast_exp2(p[i] - m_run[qs]); tsum += p[i]; }
            tsum += __shfl_xor(tsum, 16);
            tsum += __shfl_xor(tsum, 32);
            l_run[qs] += tsum;

            bf16x8 paf[2];
#pragma unroll
            for (int ks = 0; ks < 2; ++ks) {
                union { u32x4 u; bf16x8 h; } cv;
#pragma unroll
                for (int j2 = 0; j2 < 4; ++j2)
                    asm("v_cvt_pk_bf16_f32 %0, %1, %2"
                        : "=v"(cv.u[j2]) : "v"(p[ks * 8 + 2 * j2]), "v"(p[ks * 8 + 2 * j2 + 1]));
                paf[ks] = cv.h;
            }

            __builtin_amdgcn_s_setprio(1);
#pragma unroll
            for (int ks = 0; ks < 2; ++ks) {
#pragma unroll
                for (int df = 0; df < 4; ++df) {
                    const int d = df * 16 + l15;
                    int addr = d * 128 + ks * 64 + l4 * 16;
                    addr ^= (d & 7) << 4;
                    const bf16x8 vf = *(const bf16x8*)(vb + addr);
                    oacc[qs][df] = __builtin_amdgcn_mfma_f32_16x16x32_bf16(paf[ks], vf, oacc[qs][df], 0, 0, 0);
                }
            }
            __builtin_amdgcn_s_setprio(0);
        }
        // NO trailing barrier (triple-buffer makes it unnecessary)
    };

    STAGE(0, 0);
    for (int g = 0; g < 5; ++g) {
#pragma unroll
        for (int p = 0; p < 3; ++p)
            BODY(g * 3 + p, p, false);     // kt = 0..14, cur = kt%3 (static)
    }
    BODY(15, 0, true);                     // kt=15, 15%3==0

    const int b = bh / 12, h = bh - b * 12;
#pragma unroll
    for (int qs = 0; qs < 2; ++qs) {
        if (lane < 16) Flds[wave * 32 + qs * 16 + lane] = 1.f / l_run[qs];
        const f32x4 inv = *(const f32x4*)(&Flds[wave * 32 + qs * 16 + l4 * 4]);
#pragma unroll
        for (int df = 0; df < 4; ++df) {
#pragma unroll
            for (int r = 0; r < 4; ++r) {
                const int row = b * 1024 + q0 + qs * 64 + wave * 16 + l4 * 4 + r;
                const int col = h * 64 + df * 16 + l15;
                A2[(size_t)row * 768 + col] = f2bf(oacc[qs][df][r] * inv[r]);
            }
        }
    }
}

// ---------------------------------------------------------------------------
// Kernel 3: Out = A2 @ WoutT^T + b_out  (M=8192, K=768, N=768), fp32 out.
// 128x64 tile -> grid 64x12 = 768 blocks (round-8 proven).
// ---------------------------------------------------------------------------
__global__ __launch_bounds__(256) void out_gemm_kernel(
    const unsigned short* __restrict__ A2, const unsigned short* __restrict__ WT,
    const float* __restrict__ bias, float* __restrict__ Out)
{
    __shared__ unsigned short Alds[128 * 32];   // 8KB
    __shared__ unsigned short Blds[64 * 32];    // 4KB

    const int t = threadIdx.x;
    const int lane = t & 63, wave = t >> 6;
    const int l15 = lane & 15, l4 = lane >> 4;
    const int m0 = blockIdx.x * 128, n0 = blockIdx.y * 64;
    const int wr = wave >> 1, wc = wave & 1;

    f32x4 acc[4][2];
#pragma unroll
    for (int m = 0; m < 4; ++m)
#pragma unroll
        for (int n = 0; n < 2; ++n) acc[m][n] = (f32x4){0.f, 0.f, 0.f, 0.f};

    for (int k0 = 0; k0 < 768; k0 += 32) {
#pragma unroll
        for (int c = 0; c < 2; ++c) {
            const int o = wave * 1024 + lane * 16 + c * 4096;
            const int row = o >> 6, cb = o & 63;
            gload_lds16((const char*)(A2 + (size_t)(m0 + row) * 768 + k0) + cb,
                        (char*)Alds + wave * 1024 + c * 4096);
        }
        {
            const int o = t * 16;
            const int row = o >> 6, cb = o & 63;
            gload_lds16((const char*)(WT + (size_t)(n0 + row) * 768 + k0) + cb,
                        (char*)Blds + o);
        }
        __syncthreads();
        bf16x8 af[4], bfr[2];
#pragma unroll
        for (int m = 0; m < 4; ++m)
            af[m] = *(const bf16x8*)((const char*)Alds + (wr * 64 + m * 16 + l15) * 64 + l4 * 16);
#pragma unroll
        for (int n = 0; n < 2; ++n)
            bfr[n] = *(const bf16x8*)((const char*)Blds + (wc * 32 + n * 16 + l15) * 64 + l4 * 16);
#pragma unroll
        for (int m = 0; m < 4; ++m)
#pragma unroll
            for (int n = 0; n < 2; ++n)
                acc[m][n] = __builtin_amdgcn_mfma_f32_16x16x32_bf16(af[m], bfr[n], acc[m][n], 0, 0, 0);
        __syncthreads();
    }

#pragma unroll
    for (int n = 0; n < 2; ++n) {
        const int col = n0 + wc * 32 + n * 16 + l15;
        const float bv = bias[col];
#pragma unroll
        for (int m = 0; m < 4; ++m)
#pragma unroll
            for (int r = 0; r < 4; ++r) {
                const int row = m0 + wr * 64 + m * 16 + l4 * 4 + r;
                Out[(size_t)row * 768 + col] = acc[m][n][r] + bv;
            }
    }
}

// ---------------------------------------------------------------------------
extern "C" void kernel_launch(void* const* d_in, const int* in_sizes, int n_in,
                              void* d_out, int out_size, void* d_ws, size_t ws_size,
                              hipStream_t stream) {
    const float* X    = (const float*)d_in[0];
    const float* Wqkv = (const float*)d_in[1];
    const float* bqkv = (const float*)d_in[2];
    const float* Wout = (const float*)d_in[3];
    const float* bout = (const float*)d_in[4];
    float* Out = (float*)d_out;

    const size_t nq = (size_t)96 * 1024 * 64;   // 6291456 elems (12.58 MB bf16)
    unsigned short* XbA2  = (unsigned short*)d_ws;       // Xb, later reused as A2
    unsigned short* Qw    = XbA2 + nq;
    unsigned short* Kw    = Qw + nq;
    unsigned short* VTw   = Kw + nq;
    unsigned short* WqkvT = VTw + nq;                    // 2304*768
    unsigned short* WoutT = WqkvT + (size_t)2304 * 768;  // 768*768; total 55.1 MB

    hipLaunchKernelGGL(prep_kernel, dim3(3648), dim3(256), 0, stream,
                       X, XbA2, Wqkv, WqkvT, Wout, WoutT);
    hipLaunchKernelGGL(qkv_gemm_kernel, dim3(64, 18), dim3(256), 0, stream,
                       XbA2, WqkvT, bqkv, Qw, Kw, VTw);
    hipLaunchKernelGGL(attn_kernel, dim3(768), dim3(256), 0, stream,
                       Qw, Kw, VTw, XbA2);
    hipLaunchKernelGGL(out_gemm_kernel, dim3(64, 12), dim3(256), 0, stream,
                       XbA2, WoutT, bout, Out);
}

// Round 25
// 118.250 us; speedup vs baseline: 1.0973x; 1.0973x over previous
//
#include <hip/hip_runtime.h>
#include <hip/hip_bf16.h>

typedef __attribute__((ext_vector_type(4))) float f32x4;
typedef __attribute__((ext_vector_type(4))) unsigned u32x4;
typedef __attribute__((ext_vector_type(8))) short bf16x8;

#define QSCALE  (0.03608439182435161f * 1.44269504088896f)  // 768^-0.5 * log2(e)

__device__ __forceinline__ unsigned short f2bf(float f) {
    union { float f; unsigned u; } v; v.f = f;
    return (unsigned short)((v.u + 0x7FFFu + ((v.u >> 16) & 1u)) >> 16);
}

__device__ __forceinline__ float fast_exp2(float x) {
#if __has_builtin(__builtin_amdgcn_exp2f)
    return __builtin_amdgcn_exp2f(x);
#else
    return exp2f(x);
#endif
}

__device__ __forceinline__ void gload_lds16(const void* g, void* l) {
    __builtin_amdgcn_global_load_lds(
        (const __attribute__((address_space(1))) unsigned int*)g,
        (__attribute__((address_space(3))) unsigned int*)l, 16, 0, 0);
}

// ---------------------------------------------------------------------------
// Fused prepass: blocks [0,3072) xcvt X; [3072,3504) wtrans Wqkv;
// [3504,3648) wtrans Wout. Block-uniform branch.
// ---------------------------------------------------------------------------
__global__ __launch_bounds__(256) void prep_kernel(
    const float* __restrict__ X, unsigned short* __restrict__ Xb,
    const float* __restrict__ Wqkv, unsigned short* __restrict__ WqkvT,
    const float* __restrict__ Wout, unsigned short* __restrict__ WoutT)
{
    __shared__ unsigned short T[64][68];
    const int bid = blockIdx.x, t = threadIdx.x;

    if (bid < 3072) {                      // ---- xcvt: X fp32 -> bf16
        const int i = bid * 256 + t;
        f32x4 a = *(const f32x4*)(X + (size_t)i * 8);
        f32x4 b = *(const f32x4*)(X + (size_t)i * 8 + 4);
        bf16x8 w;
#pragma unroll
        for (int j = 0; j < 4; ++j) { w[j] = (short)f2bf(a[j]); w[4 + j] = (short)f2bf(b[j]); }
        *(bf16x8*)(Xb + (size_t)i * 8) = w;
        return;
    }

    const float* W; unsigned short* WT; int C, bx, by;
    if (bid < 3504) { W = Wqkv; WT = WqkvT; C = 2304; const int x = bid - 3072; bx = x % 36; by = x / 36; }
    else            { W = Wout; WT = WoutT; C = 768;  const int x = bid - 3504; bx = x % 12; by = x / 12; }
    const int R = 768;
    const int r0 = by * 64, c0 = bx * 64;
    {
        const int lr = t >> 4, lc = (t & 15) * 4;
#pragma unroll
        for (int p = 0; p < 4; ++p) {
            const float* s = W + (size_t)(r0 + lr + p * 16) * C + c0 + lc;
            f32x4 v = *(const f32x4*)s;
            unsigned short* d = &T[lr + p * 16][lc];
            d[0] = f2bf(v[0]); d[1] = f2bf(v[1]); d[2] = f2bf(v[2]); d[3] = f2bf(v[3]);
        }
    }
    __syncthreads();
    {
        const int oc = t >> 3, j0 = (t & 7) * 8;
#pragma unroll
        for (int p = 0; p < 2; ++p) {
            const int c = oc + p * 32;
            bf16x8 v;
#pragma unroll
            for (int j = 0; j < 8; ++j) v[j] = (short)T[j0 + j][c];
            *(bf16x8*)(WT + (size_t)(c0 + c) * R + r0 + j0) = v;
        }
    }
}

// ---------------------------------------------------------------------------
// Kernel 1: QKV = Xb @ WqkvT^T + b  (M=8192, K=768, N=2304). r23 proven:
// 128x128 tile, QUAD-buffered LDS (64KB), depth-2 prefetch, vmcnt(8),
// ONE barrier/iter, unroll-by-4. Epilogues: Q/K LDS restage, V transpose.
// ---------------------------------------------------------------------------
__global__ __launch_bounds__(256) void qkv_gemm_kernel(
    const unsigned short* __restrict__ Xb, const unsigned short* __restrict__ WT,
    const float* __restrict__ bias,
    unsigned short* __restrict__ Qw, unsigned short* __restrict__ Kw,
    unsigned short* __restrict__ VTw)
{
    __shared__ unsigned short SMEM[4 * 8192];

    const int t = threadIdx.x;
    const int lane = t & 63, wave = t >> 6;
    const int l15 = lane & 15, l4 = lane >> 4;
    const int m0 = blockIdx.x * 128, n0 = blockIdx.y * 128;
    const int wr = wave >> 1, wc = wave & 1;

    f32x4 acc[4][4];
#pragma unroll
    for (int m = 0; m < 4; ++m)
#pragma unroll
        for (int n = 0; n < 4; ++n) acc[m][n] = (f32x4){0.f, 0.f, 0.f, 0.f};

    auto STAGE = [&](int k0, int bufi) {
        char* base = (char*)SMEM + bufi * 16384;
#pragma unroll
        for (int c = 0; c < 2; ++c) {
            const int o = wave * 1024 + lane * 16 + c * 4096;
            const int row = o >> 6, cb = o & 63;
            gload_lds16((const char*)(Xb + (size_t)(m0 + row) * 768 + k0) + cb,
                        base + wave * 1024 + c * 4096);
            gload_lds16((const char*)(WT + (size_t)(n0 + row) * 768 + k0) + cb,
                        base + 8192 + wave * 1024 + c * 4096);
        }
    };

    STAGE(0, 0);
    STAGE(32, 1);                 // depth-2 prologue: tiles 0,1 in flight
    for (int g = 0; g < 6; ++g) {
#pragma unroll
        for (int p = 0; p < 4; ++p) {
            const int k = g * 4 + p;
            if (k < 22) {
                STAGE((k + 2) * 32, (k + 2) & 3);
                asm volatile("s_waitcnt vmcnt(8)" ::: "memory");
            } else if (k == 22) {
                asm volatile("s_waitcnt vmcnt(4)" ::: "memory");
            } else {
                asm volatile("s_waitcnt vmcnt(0)" ::: "memory");
            }
            __builtin_amdgcn_s_barrier();
            __builtin_amdgcn_sched_barrier(0);

            const char* base = (const char*)SMEM + p * 16384;
            bf16x8 af[4], bfr[4];
#pragma unroll
            for (int m = 0; m < 4; ++m)
                af[m] = *(const bf16x8*)(base + (wr * 64 + m * 16 + l15) * 64 + l4 * 16);
#pragma unroll
            for (int n = 0; n < 4; ++n)
                bfr[n] = *(const bf16x8*)(base + 8192 + (wc * 64 + n * 16 + l15) * 64 + l4 * 16);
            __builtin_amdgcn_s_setprio(1);
#pragma unroll
            for (int m = 0; m < 4; ++m)
#pragma unroll
                for (int n = 0; n < 4; ++n)
                    acc[m][n] = __builtin_amdgcn_mfma_f32_16x16x32_bf16(af[m], bfr[n], acc[m][n], 0, 0, 0);
            __builtin_amdgcn_s_setprio(0);
        }
    }
    __syncthreads();

    const int b = m0 >> 10, ntok0 = m0 & 1023;
    if (n0 < 1536) {
        const int which = n0 / 768;
        const int h0 = (n0 - which * 768) >> 6;
#pragma unroll
        for (int hh = 0; hh < 2; ++hh) {
            if (wc == hh) {
#pragma unroll
                for (int n = 0; n < 4; ++n) {
                    const int dd = n * 16 + l15;
                    const float bv = bias[n0 + hh * 64 + dd];
#pragma unroll
                    for (int m = 0; m < 4; ++m)
#pragma unroll
                        for (int r = 0; r < 4; ++r) {
                            const int ntl = wr * 64 + m * 16 + l4 * 4 + r;
                            float val = acc[m][n][r] + bv;
                            if (which == 0) val *= QSCALE;
                            SMEM[ntl * 68 + dd] = f2bf(val);
                        }
                }
            }
            __syncthreads();
            {
                unsigned short* dst = (which == 0 ? Qw : Kw)
                    + ((size_t)(b * 12 + h0 + hh) * 1024 + ntok0) * 64;
                const int k8 = (t & 7) * 8;
#pragma unroll
                for (int pass = 0; pass < 4; ++pass) {
                    const int row = pass * 32 + (t >> 3);
                    *(bf16x8*)&dst[(size_t)row * 64 + k8] =
                        *(const bf16x8*)&SMEM[row * 68 + k8];
                }
            }
            __syncthreads();
        }
    } else {
        const int h0 = (n0 - 1536) >> 6;
#pragma unroll
        for (int hh = 0; hh < 2; ++hh) {
            if (wc == hh) {
#pragma unroll
                for (int n = 0; n < 4; ++n) {
                    const int cloc = n * 16 + l15;
                    const float bv = bias[n0 + hh * 64 + cloc];
#pragma unroll
                    for (int m = 0; m < 4; ++m)
#pragma unroll
                        for (int r = 0; r < 4; ++r) {
                            const int ntl = wr * 64 + m * 16 + l4 * 4 + r;
                            SMEM[cloc * 136 + ntl] = f2bf(acc[m][n][r] + bv);
                        }
                }
            }
            __syncthreads();
            {
                const int sub = t & 15;
#pragma unroll
                for (int rep = 0; rep < 4; ++rep) {
                    const int cll = rep * 16 + (t >> 4);
                    const size_t rb = ((size_t)(b * 12 + h0 + hh) * 64 + cll) * 1024
                                      + ntok0 + sub * 8;
                    *(bf16x8*)&VTw[rb] = *(const bf16x8*)&SMEM[cll * 136 + sub * 8];
                }
            }
            __syncthreads();
        }
    }
}

// ---------------------------------------------------------------------------
// Kernel 2: flash attention, QBLK=128 (r12 proven): each wave processes TWO
// 16-row q-subtiles against the same staged K/V tile. Sigma-permuted K rows
// -> P in registers; exp2 softmax; defer-max; counted vmcnt(4) double-buffer;
// XCD-bijective swizzle (8x96).
// ---------------------------------------------------------------------------
__global__ __launch_bounds__(256) void attn_kernel(
    const unsigned short* __restrict__ Qw, const unsigned short* __restrict__ Kw,
    const unsigned short* __restrict__ VTw, unsigned short* __restrict__ A2)
{
    __shared__ unsigned short Klds[2 * 64 * 64];
    __shared__ unsigned short Vlds[2 * 64 * 64];
    __shared__ float Flds[4 * 2 * 16];

    const int t = threadIdx.x, lane = t & 63, wave = t >> 6;
    const int l15 = lane & 15, l4 = lane >> 4;
    const int wg = (blockIdx.x & 7) * 96 + (blockIdx.x >> 3);   // 768 = 8 XCD x 96
    const int qt = wg & 7, bh = wg >> 3;
    const int q0 = qt * 128;

    const size_t kvbase = (size_t)bh * 1024 * 64;
    const size_t vtbase = (size_t)bh * 64 * 1024;

    bf16x8 qf[2][2];
#pragma unroll
    for (int qs = 0; qs < 2; ++qs) {
        const unsigned short* qptr = Qw + kvbase + (size_t)(q0 + qs * 64 + wave * 16 + l15) * 64;
        qf[qs][0] = *(const bf16x8*)((const char*)qptr + l4 * 16);
        qf[qs][1] = *(const bf16x8*)((const char*)qptr + 64 + l4 * 16);
    }

    f32x4 oacc[2][4];
#pragma unroll
    for (int qs = 0; qs < 2; ++qs)
#pragma unroll
        for (int d = 0; d < 4; ++d) oacc[qs][d] = (f32x4){0.f, 0.f, 0.f, 0.f};
    float m_run[2] = {-1e30f, -1e30f}, l_run[2] = {0.f, 0.f};

    auto STAGE = [&](int kt, int bufi) {
        const int kv0 = kt * 64;
        char* kb = (char*)Klds + bufi * 8192;
        char* vb = (char*)Vlds + bufi * 8192;
#pragma unroll
        for (int c = 0; c < 2; ++c) {
            const int oo = wave * 1024 + lane * 16 + c * 4096;
            const int R = oo >> 7, w = oo & 127;
            const int sw = w ^ ((R & 7) << 4);
            const int kvs = (R & 0x23) | ((R & 0x0C) << 1) | ((R & 0x10) >> 2);
            gload_lds16((const char*)(Kw + kvbase + (size_t)(kv0 + kvs) * 64) + sw,
                        kb + wave * 1024 + c * 4096);
            gload_lds16((const char*)(VTw + vtbase + (size_t)R * 1024 + kv0) + sw,
                        vb + wave * 1024 + c * 4096);
        }
    };

    STAGE(0, 0);
    for (int kt = 0; kt < 16; ++kt) {
        const int cur = kt & 1;
        if (kt < 15) {
            STAGE(kt + 1, cur ^ 1);
            asm volatile("s_waitcnt vmcnt(4)" ::: "memory");
        } else {
            asm volatile("s_waitcnt vmcnt(0)" ::: "memory");
        }
        __builtin_amdgcn_s_barrier();
        __builtin_amdgcn_sched_barrier(0);
        const char* kb = (const char*)Klds + cur * 8192;
        const char* vb = (const char*)Vlds + cur * 8192;

#pragma unroll
        for (int qs = 0; qs < 2; ++qs) {
            f32x4 sacc[4];
#pragma unroll
            for (int i = 0; i < 4; ++i) sacc[i] = (f32x4){0.f, 0.f, 0.f, 0.f};
            __builtin_amdgcn_s_setprio(1);
#pragma unroll
            for (int ks = 0; ks < 2; ++ks) {
                const bf16x8 qq = qf[qs][ks];
#pragma unroll
                for (int kvf = 0; kvf < 4; ++kvf) {
                    const int row = kvf * 16 + l15;
                    int addr = row * 128 + ks * 64 + l4 * 16;
                    addr ^= (row & 7) << 4;
                    const bf16x8 kf = *(const bf16x8*)(kb + addr);
                    sacc[kvf] = __builtin_amdgcn_mfma_f32_16x16x32_bf16(kf, qq, sacc[kvf], 0, 0, 0);
                }
            }
            __builtin_amdgcn_s_setprio(0);

            float p[16];
            float tmax = -1e30f;
#pragma unroll
            for (int i = 0; i < 4; ++i)
#pragma unroll
                for (int r = 0; r < 4; ++r) {
                    p[i * 4 + r] = sacc[i][r];
                    tmax = fmaxf(tmax, sacc[i][r]);
                }
            tmax = fmaxf(tmax, __shfl_xor(tmax, 16));
            tmax = fmaxf(tmax, __shfl_xor(tmax, 32));

            if (!__all(tmax - m_run[qs] <= 8.f)) {
                const float mnew = fmaxf(m_run[qs], tmax);
                const float alpha = fast_exp2(m_run[qs] - mnew);
                m_run[qs] = mnew;
                if (lane < 16) Flds[wave * 32 + qs * 16 + lane] = alpha;
                const f32x4 av = *(const f32x4*)(&Flds[wave * 32 + qs * 16 + l4 * 4]);
#pragma unroll
                for (int d = 0; d < 4; ++d)
#pragma unroll
                    for (int r = 0; r < 4; ++r) oacc[qs][d][r] *= av[r];
                l_run[qs] *= alpha;
            }

            float tsum = 0.f;
#pragma unroll
            for (int i = 0; i < 16; ++i) { p[i] = fast_exp2(p[i] - m_run[qs]); tsum += p[i]; }
            tsum += __shfl_xor(tsum, 16);
            tsum += __shfl_xor(tsum, 32);
            l_run[qs] += tsum;

            bf16x8 paf[2];
#pragma unroll
            for (int ks = 0; ks < 2; ++ks) {
                union { u32x4 u; bf16x8 h; } cv;
#pragma unroll
                for (int j2 = 0; j2 < 4; ++j2)
                    asm("v_cvt_pk_bf16_f32 %0, %1, %2"
                        : "=v"(cv.u[j2]) : "v"(p[ks * 8 + 2 * j2]), "v"(p[ks * 8 + 2 * j2 + 1]));
                paf[ks] = cv.h;
            }

            __builtin_amdgcn_s_setprio(1);
#pragma unroll
            for (int ks = 0; ks < 2; ++ks) {
#pragma unroll
                for (int df = 0; df < 4; ++df) {
                    const int d = df * 16 + l15;
                    int addr = d * 128 + ks * 64 + l4 * 16;
                    addr ^= (d & 7) << 4;
                    const bf16x8 vf = *(const bf16x8*)(vb + addr);
                    oacc[qs][df] = __builtin_amdgcn_mfma_f32_16x16x32_bf16(paf[ks], vf, oacc[qs][df], 0, 0, 0);
                }
            }
            __builtin_amdgcn_s_setprio(0);
        }
        __builtin_amdgcn_s_barrier();
    }

    const int b = bh / 12, h = bh - b * 12;
#pragma unroll
    for (int qs = 0; qs < 2; ++qs) {
        if (lane < 16) Flds[wave * 32 + qs * 16 + lane] = 1.f / l_run[qs];
        const f32x4 inv = *(const f32x4*)(&Flds[wave * 32 + qs * 16 + l4 * 4]);
#pragma unroll
        for (int df = 0; df < 4; ++df) {
#pragma unroll
            for (int r = 0; r < 4; ++r) {
                const int row = b * 1024 + q0 + qs * 64 + wave * 16 + l4 * 4 + r;
                const int col = h * 64 + df * 16 + l15;
                A2[(size_t)row * 768 + col] = f2bf(oacc[qs][df][r] * inv[r]);
            }
        }
    }
}

// ---------------------------------------------------------------------------
// Kernel 3: Out = A2 @ WoutT^T + b_out  (M=8192, K=768, N=768), fp32 out.
// 128x64 tile -> grid 64x12 = 768 blocks (round-8 proven).
// ---------------------------------------------------------------------------
__global__ __launch_bounds__(256) void out_gemm_kernel(
    const unsigned short* __restrict__ A2, const unsigned short* __restrict__ WT,
    const float* __restrict__ bias, float* __restrict__ Out)
{
    __shared__ unsigned short Alds[128 * 32];   // 8KB
    __shared__ unsigned short Blds[64 * 32];    // 4KB

    const int t = threadIdx.x;
    const int lane = t & 63, wave = t >> 6;
    const int l15 = lane & 15, l4 = lane >> 4;
    const int m0 = blockIdx.x * 128, n0 = blockIdx.y * 64;
    const int wr = wave >> 1, wc = wave & 1;

    f32x4 acc[4][2];
#pragma unroll
    for (int m = 0; m < 4; ++m)
#pragma unroll
        for (int n = 0; n < 2; ++n) acc[m][n] = (f32x4){0.f, 0.f, 0.f, 0.f};

    for (int k0 = 0; k0 < 768; k0 += 32) {
#pragma unroll
        for (int c = 0; c < 2; ++c) {
            const int o = wave * 1024 + lane * 16 + c * 4096;
            const int row = o >> 6, cb = o & 63;
            gload_lds16((const char*)(A2 + (size_t)(m0 + row) * 768 + k0) + cb,
                        (char*)Alds + wave * 1024 + c * 4096);
        }
        {
            const int o = t * 16;
            const int row = o >> 6, cb = o & 63;
            gload_lds16((const char*)(WT + (size_t)(n0 + row) * 768 + k0) + cb,
                        (char*)Blds + o);
        }
        __syncthreads();
        bf16x8 af[4], bfr[2];
#pragma unroll
        for (int m = 0; m < 4; ++m)
            af[m] = *(const bf16x8*)((const char*)Alds + (wr * 64 + m * 16 + l15) * 64 + l4 * 16);
#pragma unroll
        for (int n = 0; n < 2; ++n)
            bfr[n] = *(const bf16x8*)((const char*)Blds + (wc * 32 + n * 16 + l15) * 64 + l4 * 16);
#pragma unroll
        for (int m = 0; m < 4; ++m)
#pragma unroll
            for (int n = 0; n < 2; ++n)
                acc[m][n] = __builtin_amdgcn_mfma_f32_16x16x32_bf16(af[m], bfr[n], acc[m][n], 0, 0, 0);
        __syncthreads();
    }

#pragma unroll
    for (int n = 0; n < 2; ++n) {
        const int col = n0 + wc * 32 + n * 16 + l15;
        const float bv = bias[col];
#pragma unroll
        for (int m = 0; m < 4; ++m)
#pragma unroll
            for (int r = 0; r < 4; ++r) {
                const int row = m0 + wr * 64 + m * 16 + l4 * 4 + r;
                Out[(size_t)row * 768 + col] = acc[m][n][r] + bv;
            }
    }
}

// ---------------------------------------------------------------------------
extern "C" void kernel_launch(void* const* d_in, const int* in_sizes, int n_in,
                              void* d_out, int out_size, void* d_ws, size_t ws_size,
                              hipStream_t stream) {
    const float* X    = (const float*)d_in[0];
    const float* Wqkv = (const float*)d_in[1];
    const float* bqkv = (const float*)d_in[2];
    const float* Wout = (const float*)d_in[3];
    const float* bout = (const float*)d_in[4];
    float* Out = (float*)d_out;

    const size_t nq = (size_t)96 * 1024 * 64;   // 6291456 elems (12.58 MB bf16)
    unsigned short* XbA2  = (unsigned short*)d_ws;       // Xb, later reused as A2
    unsigned short* Qw    = XbA2 + nq;
    unsigned short* Kw    = Qw + nq;
    unsigned short* VTw   = Kw + nq;
    unsigned short* WqkvT = VTw + nq;                    // 2304*768
    unsigned short* WoutT = WqkvT + (size_t)2304 * 768;  // 768*768; total 55.1 MB

    hipLaunchKernelGGL(prep_kernel, dim3(3648), dim3(256), 0, stream,
                       X, XbA2, Wqkv, WqkvT, Wout, WoutT);
    hipLaunchKernelGGL(qkv_gemm_kernel, dim3(64, 18), dim3(256), 0, stream,
                       XbA2, WqkvT, bqkv, Qw, Kw, VTw);
    hipLaunchKernelGGL(attn_kernel, dim3(768), dim3(256), 0, stream,
                       Qw, Kw, VTw, XbA2);
    hipLaunchKernelGGL(out_gemm_kernel, dim3(64, 12), dim3(256), 0, stream,
                       XbA2, WoutT, bout, Out);
}